// Round 4
// baseline (228.232 us; speedup 1.0000x reference)
//
#include <hip/hip_runtime.h>

// ROIAlign3d: x=[2,256,16,64,64] f32, rois=[64,5] -> out=[64,256,16,7,7] f32.
// R5c: block = one (batch, c, t) plane (8192 blocks). Stage the full 64x64
// plane into LDS once (exact-minimum HBM fetch: input read exactly once,
// fully coalesced float4). Then loop over the 32 rois of this batch:
// thread = (roi, ph) row; bilinear prep is separable so each thread computes
// its own y/x preps in registers -- no sample tables, no table LDS traffic.
// Plane row stride padded to 68 floats (16B aligned, 68%32=4) so taps from
// different rows hit different banks.
// vs R5b: roi->batch compaction is serial on tid 0 (no LDS atomics,
// deterministic under rocprof replay); cost hidden under plane staging.

__global__ __launch_bounds__(256) void roialign3d_kernel(
    const float* __restrict__ x, const float* __restrict__ rois,
    float* __restrict__ out)
{
    constexpr int C = 256, T = 16;
    constexpr float SCALE = 0.0625f;
    constexpr int ROWSTR = 68;               // padded LDS row stride (floats)
    constexpr int NROIS = 64;

    __shared__ float s_plane[64 * ROWSTR];   // 17,408 B
    __shared__ float s_rois[NROIS * 5];      //  1,280 B
    __shared__ int   s_rlist[NROIS];
    __shared__ int   s_nr;

    const int b   = blockIdx.x;              // plane id: ((n*C)+c)*T + t
    const int n   = b >> 12;                 // 4096 planes per batch
    const int c   = (b >> 4) & 255;
    const int t   = b & 15;
    const int tid = threadIdx.x;

    // ---- stage full plane: 1024 float4, fully coalesced, issued first ----
    {
        const float4* src = (const float4*)(x + ((size_t)b << 12));
#pragma unroll
        for (int i = 0; i < 4; ++i) {
            const int e   = tid + (i << 8);          // float4 idx 0..1023
            const int row = e >> 4, col4 = e & 15;
            const float4 v = src[e];
            *(float4*)&s_plane[row * ROWSTR + (col4 << 2)] = v;
        }
    }
    for (int i = tid; i < NROIS * 5; i += 256) s_rois[i] = rois[i];
    __syncthreads();

    // ---- compact list of rois belonging to this batch (serial, tid 0) ----
    if (tid == 0) {
        int k = 0;
        for (int j = 0; j < NROIS; ++j)
            if ((int)s_rois[j * 5] == n) s_rlist[k++] = j;
        s_nr = k;
    }
    __syncthreads();

    // ---- compute: thread = (roi-slot, ph); 32 rois x 7 ph = 224 active ----
    const int nr  = s_nr;
    const int rrl = tid / 7;
    const int ph  = tid - rrl * 7;
    if (rrl >= nr) return;
    const int rr = s_rlist[rrl];

    const float sw_ = s_rois[rr * 5 + 1] * SCALE;
    const float sh_ = s_rois[rr * 5 + 2] * SCALE;
    const float ew_ = s_rois[rr * 5 + 3] * SCALE;
    const float eh_ = s_rois[rr * 5 + 4] * SCALE;
    const float bin_w = fmaxf(ew_ - sw_, 1.0f) * (1.0f / 7.0f);
    const float bin_h = fmaxf(eh_ - sh_, 1.0f) * (1.0f / 7.0f);

    // y-prep for gy in {0.25, 0.75}; fold 0.5*valid into the y weights
    int   ro0[2], ro1[2];
    float wyh[2], wyl[2];
#pragma unroll
    for (int gy = 0; gy < 2; ++gy) {
        const float ys = sh_ + ((float)ph + (gy ? 0.75f : 0.25f)) * bin_h;
        const bool  vy = (ys >= -1.0f) && (ys <= 64.0f);
        const float yc = fminf(fmaxf(ys, 0.0f), 63.0f);
        const int   y0 = (int)yc;                    // floor, yc >= 0
        const int   y1 = min(y0 + 1, 63);
        const float ly = yc - (float)y0;
        const float m  = vy ? 0.5f : 0.0f;
        ro0[gy] = y0 * ROWSTR;
        ro1[gy] = y1 * ROWSTR;
        wyh[gy] = (1.0f - ly) * m;
        wyl[gy] = ly * m;
    }

    float accs[7];
#pragma unroll
    for (int pw = 0; pw < 7; ++pw) {
        float acc = 0.0f;
#pragma unroll
        for (int gx = 0; gx < 2; ++gx) {
            const float xs = sw_ + ((float)pw + (gx ? 0.75f : 0.25f)) * bin_w;
            const bool  vx = (xs >= -1.0f) && (xs <= 64.0f);
            const float xc = fminf(fmaxf(xs, 0.0f), 63.0f);
            const int   x0 = (int)xc;
            const int   x1 = min(x0 + 1, 63);
            const float lx = xc - (float)x0;
            const float m  = vx ? 0.5f : 0.0f;
            const float wxh = (1.0f - lx) * m, wxl = lx * m;
#pragma unroll
            for (int gy = 0; gy < 2; ++gy) {
                const float p00 = s_plane[ro0[gy] + x0];
                const float p01 = s_plane[ro0[gy] + x1];
                const float p10 = s_plane[ro1[gy] + x0];
                const float p11 = s_plane[ro1[gy] + x1];
                acc += wyh[gy] * (wxh * p00 + wxl * p01)
                     + wyl[gy] * (wxh * p10 + wxl * p11);
            }
        }
        accs[pw] = acc;
    }

    float* op = out + (size_t)(((rr * C + c) * T + t) * 49 + ph * 7);
#pragma unroll
    for (int pw = 0; pw < 7; ++pw) op[pw] = accs[pw];
}

extern "C" void kernel_launch(void* const* d_in, const int* in_sizes, int n_in,
                              void* d_out, int out_size, void* d_ws, size_t ws_size,
                              hipStream_t stream) {
    const float* x    = (const float*)d_in[0];
    const float* rois = (const float*)d_in[1];
    float* out = (float*)d_out;

    // 2 batches * 256 channels * 16 t = 8192 blocks, one input plane each
    roialign3d_kernel<<<dim3(8192), dim3(256), 0, stream>>>(x, rois, out);
}